// Round 7
// baseline (201.514 us; speedup 1.0000x reference)
//
#include <hip/hip_runtime.h>
#include <cstdint>
#include <cstddef>

// dec: [16, 3999, 512] fp32, wgt: [16, 512] fp32, out: [16, 32000] fp32
//   est[f][w] = dot(dec[f], wgt[w]);  out[8g+i] = est[g][i] + est[g-1][8+i]
//
// R7 structure: weight reads moved from LDS (ds_read_b128, CU-shared pipe,
// ~41 us/CU at 16 waves) to the SCALAR pipe: q is readfirstlane-pinned so
// weight addresses are provably uniform -> backend emits s_load from the
// read-only global buffer; FMAs take weights as SGPR operands. LDS is only
// the 16 KB reduction buffer; one barrier per block. Even/odd-k float2
// accumulators invite v_pk_fma_f32.

#define NBC     16
#define FRAMES  3999
#define EE      512
#define TOUT    32000
#define NGROUP  4000
#define GPB     63      // output groups per block (64 frame-slots)

__global__ __launch_bounds__(256, 6) void decoder_kernel(
    const float* __restrict__ dec,
    const float* __restrict__ wgt,
    float* __restrict__ out)
{
    __shared__ float red[4 * 16 * 64];   // [q][w][s], 16 KB

    const int tid   = threadIdx.x;
    const int bc    = blockIdx.x >> 6;   // 0..15
    const int chunk = blockIdx.x & 63;   // 0..63
    const int g0    = chunk * GPB;

    const int s = tid & 63;              // frame slot
    const int q = __builtin_amdgcn_readfirstlane(tid >> 6);  // SGPR-uniform

    const int f = g0 - 1 + s;
    const float vmask = (f >= 0 && f < FRAMES) ? 1.0f : 0.0f;
    const int fr = min(max(f, 0), FRAMES - 1);   // clamped row, safe loads

    const float* arow  = dec + ((size_t)bc * FRAMES + fr) * EE + q * 128;
    const float* wbase = wgt + q * 128;  // uniform (SGPR) base

    // even-k / odd-k partial sums per w
    float2 acc[16];
    #pragma unroll
    for (int w = 0; w < 16; ++w) acc[w] = make_float2(0.f, 0.f);

    #pragma unroll
    for (int c = 0; c < 8; ++c) {
        float4 xv[4];
        #pragma unroll
        for (int u = 0; u < 4; ++u)
            xv[u] = *(const float4*)(arow + c * 16 + 4 * u);  // one 64B line

        #pragma unroll
        for (int w = 0; w < 16; ++w) {
            const float* wr = wbase + w * EE + c * 16;  // uniform -> s_load
            #pragma unroll
            for (int u = 0; u < 4; ++u) {
                const float4 wq = *(const float4*)(wr + 4 * u);
                acc[w].x = fmaf(xv[u].x, wq.x, acc[w].x);
                acc[w].y = fmaf(xv[u].y, wq.y, acc[w].y);
                acc[w].x = fmaf(xv[u].z, wq.z, acc[w].x);
                acc[w].y = fmaf(xv[u].w, wq.w, acc[w].y);
            }
        }
    }

    // ---- 4-way K-split reduction via LDS ----
    #pragma unroll
    for (int w = 0; w < 16; ++w)
        red[(q * 16 + w) * 64 + s] = (acc[w].x + acc[w].y) * vmask;
    __syncthreads();

    // ---- fused overlap-add: 504 outputs, 256 threads -> 2 iterations ----
    for (int o = tid; o < GPB * 8; o += 256) {
        const int j = o >> 3;            // group offset in block, 0..62
        const int i = o & 7;             // sample within group
        const int g = g0 + j;
        if (g < NGROUP) {
            float v = 0.f;
            #pragma unroll
            for (int qq = 0; qq < 4; ++qq)
                v += red[(qq * 16 + i) * 64 + (j + 1)]      // est[g][i]
                   + red[(qq * 16 + 8 + i) * 64 + j];       // est[g-1][8+i]
            out[(size_t)bc * TOUT + g * 8 + i] = v;
        }
    }
}

extern "C" void kernel_launch(void* const* d_in, const int* in_sizes, int n_in,
                              void* d_out, int out_size, void* d_ws, size_t ws_size,
                              hipStream_t stream) {
    const float* dec = (const float*)d_in[0];   // [8,2,3999,512] fp32
    const float* wgt = (const float*)d_in[1];   // [16,512] fp32
    float* out = (float*)d_out;                 // [8,2,32000] fp32

    decoder_kernel<<<dim3(1024), dim3(256), 0, stream>>>(dec, wgt, out);
}